// Round 1
// baseline (610.310 us; speedup 1.0000x reference)
//
#include <hip/hip_runtime.h>
#include <math.h>

// Attention_Critic fused fp32 baseline.
// Block = 256 threads handles TR=64 rows. Weights streamed via 16KB LDS chunks.
// Per-thread register tile: 4 rows x 8 cols. Attention done online over n=0..6.

#define TR 64
#define LDA 132   // padded f32 pitch for activation buffers (row bank offset = 4)

__device__ __forceinline__ float lrelu(float x) { return x > 0.f ? x : 0.01f * x; }

// acc += inL[64 x KTOT] @ Wg[KTOT x 128], thread tile (r0..r0+3) x (c0..c0+7)
template<int KTOT>
__device__ __forceinline__ void mm_tile(const float* __restrict__ inL,
                                        const float* __restrict__ Wg,
                                        float* __restrict__ sW,
                                        float acc[4][8], int r0, int c0, int t)
{
    for (int kc = 0; kc < KTOT; kc += 32) {
        __syncthreads();                       // protect sW from previous readers
        const float4* src = (const float4*)(Wg + kc * 128);
        float4* dst = (float4*)sW;
        #pragma unroll
        for (int i = 0; i < 4; ++i) dst[t + 256 * i] = src[t + 256 * i];
        __syncthreads();
        #pragma unroll
        for (int k4 = 0; k4 < 8; ++k4) {
            float A4[4][4];
            #pragma unroll
            for (int i = 0; i < 4; ++i)
                *(float4*)A4[i] = *(const float4*)(inL + (r0 + i) * LDA + kc + k4 * 4);
            #pragma unroll
            for (int kq = 0; kq < 4; ++kq) {
                float w[8];
                const float* wr = sW + (k4 * 4 + kq) * 128 + c0;
                *(float4*)&w[0] = *(const float4*)(wr);
                *(float4*)&w[4] = *(const float4*)(wr + 4);
                #pragma unroll
                for (int i = 0; i < 4; ++i) {
                    float av = A4[i][kq];
                    #pragma unroll
                    for (int j = 0; j < 8; ++j)
                        acc[i][j] = fmaf(av, w[j], acc[i][j]);
                }
            }
        }
    }
}

__global__ void __launch_bounds__(256, 1)
ac_fused(const float* __restrict__ s, const float* __restrict__ a,
         const float* __restrict__ W_enc_s, const float* __restrict__ b_enc_s,
         const float* __restrict__ W_enc_sa, const float* __restrict__ b_enc_sa,
         const float* __restrict__ Wq, const float* __restrict__ Wk,
         const float* __restrict__ Wv, const float* __restrict__ bv,
         const float* __restrict__ Wo, const float* __restrict__ bo,
         const float* __restrict__ W_fc1, const float* __restrict__ b_fc1,
         const float* __restrict__ W_fc2, const float* __restrict__ b_fc2,
         float* __restrict__ out_q, float* __restrict__ out_allq, int B)
{
    __shared__ __align__(16) float sACT[TR * LDA];  // s_enc (persists to fc1)
    __shared__ __align__(16) float sQs[TR * LDA];   // Q -> attn -> h1
    __shared__ __align__(16) float sE[TR * LDA];    // staging: s_i / sa / e / ov / all_q
    __shared__ __align__(16) float sW[32 * 128];    // weight chunk (16KB)

    const int t  = threadIdx.x;
    const int tc = t & 15, tr = t >> 4;
    const int c0 = tc * 8, r0 = tr * 4;
    const int row0 = blockIdx.x * TR;
    const float inv_sqrt_d = 0.17677669529663687f;  // 1/sqrt(32)

    float acc[4][8];

    // ---- stage s_i (cols 0..95) into sE ----
    #pragma unroll
    for (int i = 0; i < 6; ++i) {
        int idx = t + 256 * i;
        int r = idx / 24, c4 = idx % 24;
        *(float4*)(sE + r * LDA + c4 * 4) =
            *(const float4*)(s + (row0 + r) * 768 + c4 * 4);
    }

    // ---- s_enc = leaky(s_i @ W_enc_s + b_enc_s) -> sACT ----
    #pragma unroll
    for (int i = 0; i < 4; ++i)
        #pragma unroll
        for (int j = 0; j < 8; ++j) acc[i][j] = 0.f;
    mm_tile<96>(sE, W_enc_s, sW, acc, r0, c0, t);
    {
        float bb[8];
        *(float4*)&bb[0] = *(const float4*)(b_enc_s + c0);
        *(float4*)&bb[4] = *(const float4*)(b_enc_s + c0 + 4);
        #pragma unroll
        for (int i = 0; i < 4; ++i)
            #pragma unroll
            for (int j = 0; j < 8; ++j)
                sACT[(r0 + i) * LDA + c0 + j] = lrelu(acc[i][j] + bb[j]);
    }

    // ---- Q = s_enc @ Wq -> sQs (no bias / act) ----
    #pragma unroll
    for (int i = 0; i < 4; ++i)
        #pragma unroll
        for (int j = 0; j < 8; ++j) acc[i][j] = 0.f;
    mm_tile<128>(sACT, Wq, sW, acc, r0, c0, t);
    #pragma unroll
    for (int i = 0; i < 4; ++i)
        #pragma unroll
        for (int j = 0; j < 8; ++j)
            sQs[(r0 + i) * LDA + c0 + j] = acc[i][j];

    // ---- online attention over the 7 other agents ----
    float attnacc[4][8];
    #pragma unroll
    for (int i = 0; i < 4; ++i)
        #pragma unroll
        for (int j = 0; j < 8; ++j) attnacc[i][j] = 0.f;
    float m_run[4], l_run[4];
    #pragma unroll
    for (int i = 0; i < 4; ++i) { m_run[i] = -INFINITY; l_run[i] = 0.f; }

    float bvv[8];
    *(float4*)&bvv[0] = *(const float4*)(bv + c0);
    *(float4*)&bvv[4] = *(const float4*)(bv + c0 + 4);

    for (int n = 0; n < 7; ++n) {
        __syncthreads();   // previous readers of sE are done
        // stage sa = [s_others[n] (96) | a_others[n] (32)] into sE
        #pragma unroll
        for (int i = 0; i < 6; ++i) {
            int idx = t + 256 * i;
            int r = idx / 24, c4 = idx % 24;
            *(float4*)(sE + r * LDA + c4 * 4) =
                *(const float4*)(s + (row0 + r) * 768 + 96 + 96 * n + c4 * 4);
        }
        #pragma unroll
        for (int i = 0; i < 2; ++i) {
            int idx = t + 256 * i;
            int r = idx / 8, c4 = idx % 8;
            *(float4*)(sE + r * LDA + 96 + c4 * 4) =
                *(const float4*)(a + (row0 + r) * 256 + 32 + 32 * n + c4 * 4);
        }

        // e = leaky(sa @ W_enc_sa[n] + b_enc_sa[n])
        #pragma unroll
        for (int i = 0; i < 4; ++i)
            #pragma unroll
            for (int j = 0; j < 8; ++j) acc[i][j] = 0.f;
        mm_tile<128>(sE, W_enc_sa + n * 128 * 128, sW, acc, r0, c0, t);
        float e[4][8];
        {
            float bb[8];
            *(float4*)&bb[0] = *(const float4*)(b_enc_sa + n * 128 + c0);
            *(float4*)&bb[4] = *(const float4*)(b_enc_sa + n * 128 + c0 + 4);
            #pragma unroll
            for (int i = 0; i < 4; ++i)
                #pragma unroll
                for (int j = 0; j < 8; ++j) e[i][j] = lrelu(acc[i][j] + bb[j]);
        }
        __syncthreads();   // all reads of sa finished
        #pragma unroll
        for (int i = 0; i < 4; ++i)
            #pragma unroll
            for (int j = 0; j < 8; ++j)
                sE[(r0 + i) * LDA + c0 + j] = e[i][j];

        // K_n = e @ Wk ; scores via cross-lane reduce against Q
        #pragma unroll
        for (int i = 0; i < 4; ++i)
            #pragma unroll
            for (int j = 0; j < 8; ++j) acc[i][j] = 0.f;
        mm_tile<128>(sE, Wk, sW, acc, r0, c0, t);

        float pr[4], corr[4];
        #pragma unroll
        for (int i = 0; i < 4; ++i) {
            float q8[8];
            *(float4*)&q8[0] = *(const float4*)(sQs + (r0 + i) * LDA + c0);
            *(float4*)&q8[4] = *(const float4*)(sQs + (r0 + i) * LDA + c0 + 4);
            float p = 0.f;
            #pragma unroll
            for (int j = 0; j < 8; ++j) p = fmaf(q8[j], acc[i][j], p);
            p += __shfl_xor(p, 1);   // reduce over the 4 lanes of this head
            p += __shfl_xor(p, 2);
            float sc = p * inv_sqrt_d;
            float mnew = fmaxf(m_run[i], sc);
            pr[i]   = __expf(sc - mnew);
            corr[i] = __expf(m_run[i] - mnew);
            l_run[i] = l_run[i] * corr[i] + pr[i];
            m_run[i] = mnew;
        }

        // V_n = leaky(e @ Wv + bv); attnacc = attnacc*corr + pr*V
        #pragma unroll
        for (int i = 0; i < 4; ++i)
            #pragma unroll
            for (int j = 0; j < 8; ++j) acc[i][j] = 0.f;
        mm_tile<128>(sE, Wv, sW, acc, r0, c0, t);
        #pragma unroll
        for (int i = 0; i < 4; ++i)
            #pragma unroll
            for (int j = 0; j < 8; ++j) {
                float v = lrelu(acc[i][j] + bvv[j]);
                attnacc[i][j] = fmaf(attnacc[i][j], corr[i], pr[i] * v);
            }
    }

    // ---- attn -> sQs (Q is dead) ----
    __syncthreads();
    {
        float rl[4];
        #pragma unroll
        for (int i = 0; i < 4; ++i) rl[i] = 1.f / l_run[i];
        #pragma unroll
        for (int i = 0; i < 4; ++i)
            #pragma unroll
            for (int j = 0; j < 8; ++j)
                sQs[(r0 + i) * LDA + c0 + j] = attnacc[i][j] * rl[i];
    }

    // ---- other_values = attn @ Wo + bo ----
    #pragma unroll
    for (int i = 0; i < 4; ++i)
        #pragma unroll
        for (int j = 0; j < 8; ++j) acc[i][j] = 0.f;
    mm_tile<128>(sQs, Wo, sW, acc, r0, c0, t);
    float ov[4][8];
    {
        float bb[8];
        *(float4*)&bb[0] = *(const float4*)(bo + c0);
        *(float4*)&bb[4] = *(const float4*)(bo + c0 + 4);
        #pragma unroll
        for (int i = 0; i < 4; ++i)
            #pragma unroll
            for (int j = 0; j < 8; ++j) ov[i][j] = acc[i][j] + bb[j];
    }
    __syncthreads();
    #pragma unroll
    for (int i = 0; i < 4; ++i)
        #pragma unroll
        for (int j = 0; j < 8; ++j)
            sE[(r0 + i) * LDA + c0 + j] = ov[i][j];

    // ---- h1 = leaky([s_enc | ov] @ W_fc1 + b_fc1) -> sQs ----
    #pragma unroll
    for (int i = 0; i < 4; ++i)
        #pragma unroll
        for (int j = 0; j < 8; ++j) acc[i][j] = 0.f;
    mm_tile<128>(sACT, W_fc1, sW, acc, r0, c0, t);
    mm_tile<128>(sE, W_fc1 + 128 * 128, sW, acc, r0, c0, t);
    __syncthreads();
    {
        float bb[8];
        *(float4*)&bb[0] = *(const float4*)(b_fc1 + c0);
        *(float4*)&bb[4] = *(const float4*)(b_fc1 + c0 + 4);
        #pragma unroll
        for (int i = 0; i < 4; ++i)
            #pragma unroll
            for (int j = 0; j < 8; ++j)
                sQs[(r0 + i) * LDA + c0 + j] = lrelu(acc[i][j] + bb[j]);
    }

    // ---- all_q = h1 @ W_fc2 + b_fc2 (128 -> 32) ----
    __syncthreads();
    {
        const float4* src = (const float4*)W_fc2;
        float4* dst = (float4*)sW;
        #pragma unroll
        for (int i = 0; i < 4; ++i) dst[t + 256 * i] = src[t + 256 * i];
    }
    __syncthreads();
    float aq[4][2];
    #pragma unroll
    for (int i = 0; i < 4; ++i) { aq[i][0] = 0.f; aq[i][1] = 0.f; }
    for (int k4 = 0; k4 < 32; ++k4) {
        float A4[4][4];
        #pragma unroll
        for (int i = 0; i < 4; ++i)
            *(float4*)A4[i] = *(const float4*)(sQs + (r0 + i) * LDA + k4 * 4);
        #pragma unroll
        for (int kq = 0; kq < 4; ++kq) {
            float2 w = *(const float2*)(sW + (k4 * 4 + kq) * 32 + 2 * tc);
            #pragma unroll
            for (int i = 0; i < 4; ++i) {
                aq[i][0] = fmaf(A4[i][kq], w.x, aq[i][0]);
                aq[i][1] = fmaf(A4[i][kq], w.y, aq[i][1]);
            }
        }
    }
    {
        float2 b2 = *(const float2*)(b_fc2 + 2 * tc);
        #pragma unroll
        for (int i = 0; i < 4; ++i) { aq[i][0] += b2.x; aq[i][1] += b2.y; }
    }
    // store all_q to global
    #pragma unroll
    for (int i = 0; i < 4; ++i) {
        float2 v; v.x = aq[i][0]; v.y = aq[i][1];
        *(float2*)(out_allq + (row0 + r0 + i) * 32 + 2 * tc) = v;
    }
    // stash all_q in sE as [64][32] for the gather
    __syncthreads();
    #pragma unroll
    for (int i = 0; i < 4; ++i) {
        float2 v; v.x = aq[i][0]; v.y = aq[i][1];
        *(float2*)(sE + (r0 + i) * 32 + 2 * tc) = v;
    }
    __syncthreads();

    // ---- q = all_q[argmax(a[:, :32])] ----
    if (t < TR) {
        int row = row0 + t;
        const float4* ar = (const float4*)(a + row * 256);
        float best = -INFINITY; int bi = 0;
        #pragma unroll
        for (int jj = 0; jj < 8; ++jj) {
            float4 v = ar[jj];
            float vv[4] = {v.x, v.y, v.z, v.w};
            #pragma unroll
            for (int e2 = 0; e2 < 4; ++e2) {
                if (vv[e2] > best) { best = vv[e2]; bi = jj * 4 + e2; }
            }
        }
        out_q[row] = sE[t * 32 + bi];
    }
}

extern "C" void kernel_launch(void* const* d_in, const int* in_sizes, int n_in,
                              void* d_out, int out_size, void* d_ws, size_t ws_size,
                              hipStream_t stream)
{
    (void)n_in; (void)d_ws; (void)ws_size; (void)out_size;
    const float* s        = (const float*)d_in[0];
    const float* a        = (const float*)d_in[1];
    const float* W_enc_s  = (const float*)d_in[2];
    const float* b_enc_s  = (const float*)d_in[3];
    const float* W_enc_sa = (const float*)d_in[4];
    const float* b_enc_sa = (const float*)d_in[5];
    const float* Wq       = (const float*)d_in[6];
    const float* Wk       = (const float*)d_in[7];
    const float* Wv       = (const float*)d_in[8];
    const float* bv       = (const float*)d_in[9];
    const float* Wo       = (const float*)d_in[10];
    const float* bo       = (const float*)d_in[11];
    const float* W_fc1    = (const float*)d_in[12];
    const float* b_fc1    = (const float*)d_in[13];
    const float* W_fc2    = (const float*)d_in[14];
    const float* b_fc2    = (const float*)d_in[15];

    int B = in_sizes[0] / 768;
    float* out_q    = (float*)d_out;
    float* out_allq = out_q + B;

    dim3 grid(B / TR), block(256);
    ac_fused<<<grid, block, 0, stream>>>(s, a, W_enc_s, b_enc_s, W_enc_sa, b_enc_sa,
                                         Wq, Wk, Wv, bv, Wo, bo,
                                         W_fc1, b_fc1, W_fc2, b_fc2,
                                         out_q, out_allq, B);
}

// Round 2
// 157.163 us; speedup vs baseline: 3.8833x; 3.8833x over previous
//
#include <hip/hip_runtime.h>
#include <math.h>

// MFMA bf16 rewrite. Transposed dataflow: all matmuls compute C^T[out_feat][row]
// via D = A*B with A = W^T fragments (global bf16, contiguous 16B/lane) and
// B = activation fragments (LDS [row][feat] bf16, contiguous 16B/lane).
// mfma_f32_16x16x32_bf16 layouts (HW-verified per guide):
//   A[m][k]: m = lane&15, k = (lane>>4)*8 + i
//   B[k][n]: n = lane&15, k = (lane>>4)*8 + i
//   D[m][n]: n = lane&15, m = (lane>>4)*4 + reg
// Attention: head dim lands on (lane>>4, reg) -> QK dot = 16 FMA + shfl_xor(16,32),
// softmax state lane-local per (head, col-tile).

typedef __attribute__((ext_vector_type(8))) short bf16x8;
typedef __attribute__((ext_vector_type(4))) float f32x4;

#define PITCH 136   // bf16 pitch (272B): b128 frag reads spread uniformly over banks
#define TRB 64

__device__ __forceinline__ float lrelu(float x){ return x > 0.f ? x : 0.01f * x; }

__device__ __forceinline__ unsigned short f2bf(float x){
    union { float f; unsigned u; } c; c.f = x;
    unsigned u = c.u; u += 0x7fffu + ((u >> 16) & 1u);
    return (unsigned short)(u >> 16);
}

__device__ __forceinline__ bf16x8 ldA(const unsigned short* __restrict__ WT, int K,
                                      int m0, int kc, int lane){
    return *(const bf16x8*)(WT + (m0 + (lane & 15)) * K + kc * 32 + (lane >> 4) * 8);
}
__device__ __forceinline__ bf16x8 ldB(const unsigned short* L, int r0, int kc, int lane){
    return *(const bf16x8*)(L + (r0 + (lane & 15)) * PITCH + kc * 32 + (lane >> 4) * 8);
}

template<int NMT, int NNT, int NKC>
__device__ __forceinline__ void mmT(const unsigned short* __restrict__ WT, int K, int M0,
                                    const unsigned short* Ls, int N0, int lane,
                                    f32x4 acc[NMT][NNT])
{
#pragma unroll
    for (int kc = 0; kc < NKC; ++kc) {
        bf16x8 b[NNT];
#pragma unroll
        for (int nt = 0; nt < NNT; ++nt) b[nt] = ldB(Ls, N0 + nt * 16, kc, lane);
#pragma unroll
        for (int mt = 0; mt < NMT; ++mt) {
            bf16x8 av = ldA(WT, K, M0 + mt * 16, kc, lane);
#pragma unroll
            for (int nt = 0; nt < NNT; ++nt)
                acc[mt][nt] = __builtin_amdgcn_mfma_f32_16x16x32_bf16(av, b[nt], acc[mt][nt], 0, 0, 0);
        }
    }
}

// ---- weight prep: fp32 W[in][out] -> bf16 W^T[out][in] packed in d_ws ----
// offsets (bf16 elems): encS_T 0 (128x96), saT 12288 (7x128x128), qT 126976,
// kT 143360, vT 159744, oT 176128, w1T 192512 (128x256), w2T 225280 (32x128). total 229376.
__global__ void wprep(const float* __restrict__ Ws, const float* __restrict__ Wsa,
                      const float* __restrict__ Wq_, const float* __restrict__ Wk_,
                      const float* __restrict__ Wv_, const float* __restrict__ Wo_,
                      const float* __restrict__ W1, const float* __restrict__ W2,
                      unsigned short* __restrict__ o)
{
    int id = blockIdx.x * 256 + threadIdx.x;
    if (id >= 229376) return;
    float v;
    if (id < 12288)        { int q = id / 96, f = id - q * 96;                         v = Ws[f * 128 + q]; }
    else if (id < 126976)  { int li = id - 12288; int n = li >> 14; int r = li & 16383;
                             int q = r >> 7, f = r & 127;                              v = Wsa[n * 16384 + f * 128 + q]; }
    else if (id < 143360)  { int li = id - 126976; int q = li >> 7, f = li & 127;      v = Wq_[f * 128 + q]; }
    else if (id < 159744)  { int li = id - 143360; int q = li >> 7, f = li & 127;      v = Wk_[f * 128 + q]; }
    else if (id < 176128)  { int li = id - 159744; int q = li >> 7, f = li & 127;      v = Wv_[f * 128 + q]; }
    else if (id < 192512)  { int li = id - 176128; int q = li >> 7, f = li & 127;      v = Wo_[f * 128 + q]; }
    else if (id < 225280)  { int li = id - 192512; int q = li >> 8, f = li & 255;      v = W1[f * 128 + q]; }
    else                   { int li = id - 225280; int q = li >> 7, f = li & 127;      v = W2[f * 32 + q]; }
    o[id] = f2bf(v);
}

__global__ void __launch_bounds__(256, 2)
ac_mfma(const float* __restrict__ s, const float* __restrict__ a,
        const unsigned short* __restrict__ WS,
        const float* __restrict__ b_enc_s, const float* __restrict__ b_enc_sa,
        const float* __restrict__ bv, const float* __restrict__ bo,
        const float* __restrict__ b_fc1, const float* __restrict__ b_fc2,
        float* __restrict__ out_q, float* __restrict__ out_allq)
{
    __shared__ unsigned short bufA[TRB * PITCH];  // staging / attn / h1
    __shared__ unsigned short sENC[TRB * PITCH];  // s_enc (persists)
    __shared__ unsigned short sE[TRB * PITCH];    // e / ov ; overlaid f32 allq at end

    const int t = threadIdx.x, lane = t & 63, wid = t >> 6;
    const int wm = wid >> 1, wn = wid & 1;
    const int M0 = 64 * wm, N0 = 32 * wn;
    const int l15 = lane & 15, l4 = lane >> 4;
    const int row0 = blockIdx.x * TRB;
    const float rsd = 0.17677669529663687f;  // 1/sqrt(32)

    const unsigned short* WencST = WS;
    const unsigned short* WsaT   = WS + 12288;
    const unsigned short* WqT    = WS + 126976;
    const unsigned short* WkT    = WS + 143360;
    const unsigned short* WvT    = WS + 159744;
    const unsigned short* WoT    = WS + 176128;
    const unsigned short* W1T    = WS + 192512;
    const unsigned short* W2T    = WS + 225280;

    // ---- stage s_i (64 x 96) -> bufA ----
#pragma unroll
    for (int i = 0; i < 6; ++i) {
        int idx = t + 256 * i; int r = idx / 24, c4 = idx % 24;
        float4 v = *(const float4*)(s + (size_t)(row0 + r) * 768 + c4 * 4);
        ushort4 p; p.x = f2bf(v.x); p.y = f2bf(v.y); p.z = f2bf(v.z); p.w = f2bf(v.w);
        *(ushort4*)(bufA + r * PITCH + c4 * 4) = p;
    }
    __syncthreads();

    // ---- s_enc^T = lrelu(WencS^T @ s_i^T + b) -> sENC[b][f] ----
    {
        f32x4 acc[4][2];
#pragma unroll
        for (int mt = 0; mt < 4; ++mt)
#pragma unroll
            for (int nt = 0; nt < 2; ++nt) acc[mt][nt] = (f32x4){0.f, 0.f, 0.f, 0.f};
        mmT<4, 2, 3>(WencST, 96, M0, bufA, N0, lane, acc);
#pragma unroll
        for (int mt = 0; mt < 4; ++mt) {
            float4 bb = *(const float4*)(b_enc_s + M0 + mt * 16 + l4 * 4);
#pragma unroll
            for (int nt = 0; nt < 2; ++nt) {
                ushort4 p;
                p.x = f2bf(lrelu(acc[mt][nt][0] + bb.x));
                p.y = f2bf(lrelu(acc[mt][nt][1] + bb.y));
                p.z = f2bf(lrelu(acc[mt][nt][2] + bb.z));
                p.w = f2bf(lrelu(acc[mt][nt][3] + bb.w));
                *(ushort4*)(sENC + (N0 + nt * 16 + l15) * PITCH + M0 + mt * 16 + l4 * 4) = p;
            }
        }
    }
    __syncthreads();

    // ---- Q^T (wave-local, stays in regs): q[mt][nt][r] = Q[b][M0+mt*16+l4*4+r] ----
    f32x4 q[4][2];
#pragma unroll
    for (int mt = 0; mt < 4; ++mt)
#pragma unroll
        for (int nt = 0; nt < 2; ++nt) q[mt][nt] = (f32x4){0.f, 0.f, 0.f, 0.f};
    mmT<4, 2, 4>(WqT, 128, M0, sENC, N0, lane, q);

    float4 bvf[4];
#pragma unroll
    for (int mt = 0; mt < 4; ++mt) bvf[mt] = *(const float4*)(bv + M0 + mt * 16 + l4 * 4);

    f32x4 atn[4][2];
#pragma unroll
    for (int mt = 0; mt < 4; ++mt)
#pragma unroll
        for (int nt = 0; nt < 2; ++nt) atn[mt][nt] = (f32x4){0.f, 0.f, 0.f, 0.f};
    float m_[2][2], l_[2][2];
#pragma unroll
    for (int h = 0; h < 2; ++h)
#pragma unroll
        for (int nt = 0; nt < 2; ++nt) { m_[h][nt] = -INFINITY; l_[h][nt] = 0.f; }

    // ---- online attention over 7 agents ----
    for (int n = 0; n < 7; ++n) {
        // stage sa = [s_others(96) | a_others(32)] -> bufA
#pragma unroll
        for (int i = 0; i < 6; ++i) {
            int idx = t + 256 * i; int r = idx / 24, c4 = idx % 24;
            float4 v = *(const float4*)(s + (size_t)(row0 + r) * 768 + 96 + 96 * n + c4 * 4);
            ushort4 p; p.x = f2bf(v.x); p.y = f2bf(v.y); p.z = f2bf(v.z); p.w = f2bf(v.w);
            *(ushort4*)(bufA + r * PITCH + c4 * 4) = p;
        }
#pragma unroll
        for (int i = 0; i < 2; ++i) {
            int idx = t + 256 * i; int r = idx / 8, c4 = idx % 8;
            float4 v = *(const float4*)(a + (size_t)(row0 + r) * 256 + 32 + 32 * n + c4 * 4);
            ushort4 p; p.x = f2bf(v.x); p.y = f2bf(v.y); p.z = f2bf(v.z); p.w = f2bf(v.w);
            *(ushort4*)(bufA + r * PITCH + 96 + c4 * 4) = p;
        }
        __syncthreads();                                  // S1: staging visible

        f32x4 eacc[4][2];
#pragma unroll
        for (int mt = 0; mt < 4; ++mt)
#pragma unroll
            for (int nt = 0; nt < 2; ++nt) eacc[mt][nt] = (f32x4){0.f, 0.f, 0.f, 0.f};
        mmT<4, 2, 4>(WsaT + n * 16384, 128, M0, bufA, N0, lane, eacc);
        __syncthreads();                                  // S2: prev-iter sE readers done
#pragma unroll
        for (int mt = 0; mt < 4; ++mt) {
            float4 bb = *(const float4*)(b_enc_sa + n * 128 + M0 + mt * 16 + l4 * 4);
#pragma unroll
            for (int nt = 0; nt < 2; ++nt) {
                ushort4 p;
                p.x = f2bf(lrelu(eacc[mt][nt][0] + bb.x));
                p.y = f2bf(lrelu(eacc[mt][nt][1] + bb.y));
                p.z = f2bf(lrelu(eacc[mt][nt][2] + bb.z));
                p.w = f2bf(lrelu(eacc[mt][nt][3] + bb.w));
                *(ushort4*)(sE + (N0 + nt * 16 + l15) * PITCH + M0 + mt * 16 + l4 * 4) = p;
            }
        }
        __syncthreads();                                  // S3: e visible

        // K^T for this wave's 2 heads
        f32x4 kv[4][2];
#pragma unroll
        for (int mt = 0; mt < 4; ++mt)
#pragma unroll
            for (int nt = 0; nt < 2; ++nt) kv[mt][nt] = (f32x4){0.f, 0.f, 0.f, 0.f};
        mmT<4, 2, 4>(WkT, 128, M0, sE, N0, lane, kv);

        float pr[2][2], corr[2][2];
#pragma unroll
        for (int h = 0; h < 2; ++h)
#pragma unroll
            for (int nt = 0; nt < 2; ++nt) {
                float p = 0.f;
#pragma unroll
                for (int mi = 0; mi < 2; ++mi) {
                    int mt = 2 * h + mi;
#pragma unroll
                    for (int r = 0; r < 4; ++r) p = fmaf(q[mt][nt][r], kv[mt][nt][r], p);
                }
                p += __shfl_xor(p, 16);
                p += __shfl_xor(p, 32);
                float sc = p * rsd;
                float mo = m_[h][nt], mn = fmaxf(mo, sc);
                pr[h][nt]   = __expf(sc - mn);
                corr[h][nt] = __expf(mo - mn);
                l_[h][nt] = l_[h][nt] * corr[h][nt] + pr[h][nt];
                m_[h][nt] = mn;
            }

        // V^T, online accumulate
#pragma unroll
        for (int mt = 0; mt < 4; ++mt)
#pragma unroll
            for (int nt = 0; nt < 2; ++nt) kv[mt][nt] = (f32x4){0.f, 0.f, 0.f, 0.f};
        mmT<4, 2, 4>(WvT, 128, M0, sE, N0, lane, kv);
#pragma unroll
        for (int mt = 0; mt < 4; ++mt) {
            int h = mt >> 1;
#pragma unroll
            for (int nt = 0; nt < 2; ++nt)
#pragma unroll
                for (int r = 0; r < 4; ++r) {
                    float vv = lrelu(kv[mt][nt][r] + ((const float*)&bvf[mt])[r]);
                    atn[mt][nt][r] = fmaf(atn[mt][nt][r], corr[h][nt], pr[h][nt] * vv);
                }
        }
    }

    // ---- attn / l -> bufA[b][hd] ----
#pragma unroll
    for (int mt = 0; mt < 4; ++mt) {
        int h = mt >> 1;
#pragma unroll
        for (int nt = 0; nt < 2; ++nt) {
            float inv = 1.f / l_[h][nt];
            ushort4 p;
            p.x = f2bf(atn[mt][nt][0] * inv);
            p.y = f2bf(atn[mt][nt][1] * inv);
            p.z = f2bf(atn[mt][nt][2] * inv);
            p.w = f2bf(atn[mt][nt][3] * inv);
            *(ushort4*)(bufA + (N0 + nt * 16 + l15) * PITCH + M0 + mt * 16 + l4 * 4) = p;
        }
    }
    __syncthreads();

    // ---- ov^T = Wo^T @ attn^T + bo -> sE[b][o] ----
    {
        f32x4 acc[4][2];
#pragma unroll
        for (int mt = 0; mt < 4; ++mt)
#pragma unroll
            for (int nt = 0; nt < 2; ++nt) acc[mt][nt] = (f32x4){0.f, 0.f, 0.f, 0.f};
        mmT<4, 2, 4>(WoT, 128, M0, bufA, N0, lane, acc);
#pragma unroll
        for (int mt = 0; mt < 4; ++mt) {
            float4 bb = *(const float4*)(bo + M0 + mt * 16 + l4 * 4);
#pragma unroll
            for (int nt = 0; nt < 2; ++nt) {
                ushort4 p;
                p.x = f2bf(acc[mt][nt][0] + bb.x);
                p.y = f2bf(acc[mt][nt][1] + bb.y);
                p.z = f2bf(acc[mt][nt][2] + bb.z);
                p.w = f2bf(acc[mt][nt][3] + bb.w);
                *(ushort4*)(sE + (N0 + nt * 16 + l15) * PITCH + M0 + mt * 16 + l4 * 4) = p;
            }
        }
    }
    __syncthreads();

    // ---- h1^T = lrelu(W1^T @ [senc|ov]^T + b1) -> bufA[b][h] ----
    {
        f32x4 acc[4][2];
#pragma unroll
        for (int mt = 0; mt < 4; ++mt)
#pragma unroll
            for (int nt = 0; nt < 2; ++nt) acc[mt][nt] = (f32x4){0.f, 0.f, 0.f, 0.f};
        mmT<4, 2, 4>(W1T, 256, M0, sENC, N0, lane, acc);        // k = 0..127
        mmT<4, 2, 4>(W1T + 128, 256, M0, sE, N0, lane, acc);    // k = 128..255
        __syncthreads();   // Wo-phase bufA readers done (already true), h1 write below
#pragma unroll
        for (int mt = 0; mt < 4; ++mt) {
            float4 bb = *(const float4*)(b_fc1 + M0 + mt * 16 + l4 * 4);
#pragma unroll
            for (int nt = 0; nt < 2; ++nt) {
                ushort4 p;
                p.x = f2bf(lrelu(acc[mt][nt][0] + bb.x));
                p.y = f2bf(lrelu(acc[mt][nt][1] + bb.y));
                p.z = f2bf(lrelu(acc[mt][nt][2] + bb.z));
                p.w = f2bf(lrelu(acc[mt][nt][3] + bb.w));
                *(ushort4*)(bufA + (N0 + nt * 16 + l15) * PITCH + M0 + mt * 16 + l4 * 4) = p;
            }
        }
    }
    __syncthreads();

    // ---- all_q^T = W2^T @ h1^T + b2 ; each wave: rows 16*wid, M-tiles 0..1 ----
    float* sQf = (float*)sE;   // overlay (h1 reads of sE are done)
    {
        f32x4 qa[2][1];
        qa[0][0] = (f32x4){0.f, 0.f, 0.f, 0.f};
        qa[1][0] = (f32x4){0.f, 0.f, 0.f, 0.f};
        mmT<2, 1, 4>(W2T, 128, 0, bufA, 16 * wid, lane, qa);
#pragma unroll
        for (int mt = 0; mt < 2; ++mt) {
            float4 bb = *(const float4*)(b_fc2 + mt * 16 + l4 * 4);
            float v0 = qa[mt][0][0] + bb.x, v1 = qa[mt][0][1] + bb.y;
            float v2 = qa[mt][0][2] + bb.z, v3 = qa[mt][0][3] + bb.w;
            int b = 16 * wid + l15, o = mt * 16 + l4 * 4;
            *(float4*)(out_allq + (size_t)(row0 + b) * 32 + o) = make_float4(v0, v1, v2, v3);
            sQf[b * 33 + o + 0] = v0; sQf[b * 33 + o + 1] = v1;
            sQf[b * 33 + o + 2] = v2; sQf[b * 33 + o + 3] = v3;
        }
    }
    __syncthreads();

    // ---- q = all_q[argmax(a[:, :32])] ----
    if (t < TRB) {
        int row = row0 + t;
        const float4* ar = (const float4*)(a + (size_t)row * 256);
        float best = -INFINITY; int bi = 0;
#pragma unroll
        for (int jj = 0; jj < 8; ++jj) {
            float4 v = ar[jj];
            float vv[4] = {v.x, v.y, v.z, v.w};
#pragma unroll
            for (int e2 = 0; e2 < 4; ++e2)
                if (vv[e2] > best) { best = vv[e2]; bi = jj * 4 + e2; }
        }
        out_q[row] = sQf[t * 33 + bi];
    }
}

extern "C" void kernel_launch(void* const* d_in, const int* in_sizes, int n_in,
                              void* d_out, int out_size, void* d_ws, size_t ws_size,
                              hipStream_t stream)
{
    (void)n_in; (void)out_size; (void)ws_size;
    const float* s        = (const float*)d_in[0];
    const float* a        = (const float*)d_in[1];
    const float* W_enc_s  = (const float*)d_in[2];
    const float* b_enc_s  = (const float*)d_in[3];
    const float* W_enc_sa = (const float*)d_in[4];
    const float* b_enc_sa = (const float*)d_in[5];
    const float* Wq       = (const float*)d_in[6];
    const float* Wk       = (const float*)d_in[7];
    const float* Wv       = (const float*)d_in[8];
    const float* bv       = (const float*)d_in[9];
    const float* Wo       = (const float*)d_in[10];
    const float* bo       = (const float*)d_in[11];
    const float* W_fc1    = (const float*)d_in[12];
    const float* b_fc1    = (const float*)d_in[13];
    const float* W_fc2    = (const float*)d_in[14];
    const float* b_fc2    = (const float*)d_in[15];

    int B = in_sizes[0] / 768;
    float* out_q    = (float*)d_out;
    float* out_allq = out_q + B;
    unsigned short* WS = (unsigned short*)d_ws;

    wprep<<<dim3(896), dim3(256), 0, stream>>>(W_enc_s, W_enc_sa, Wq, Wk, Wv, Wo,
                                               W_fc1, W_fc2, WS);
    ac_mfma<<<dim3(B / TRB), dim3(256), 0, stream>>>(s, a, WS, b_enc_s, b_enc_sa,
                                                     bv, bo, b_fc1, b_fc2,
                                                     out_q, out_allq);
}

// Round 3
// 150.414 us; speedup vs baseline: 4.0575x; 1.0449x over previous
//
#include <hip/hip_runtime.h>
#include <math.h>

// R3: TRB=32, 4 blocks/CU (16 waves/CU), 2 barriers per agent iteration,
// register-prefetched staging (issue-early / write-late), double-buffered e-tile.
// Transposed MFMA dataflow as R2: C^T[out][row] = W^T frags (global/L2) x act frags (LDS).
// Wave wid owns out-feature slice M0=32*wid == attention head wid.

typedef __attribute__((ext_vector_type(8))) short bf16x8;
typedef __attribute__((ext_vector_type(4))) float f32x4;

#define PITCH 136   // bf16 pitch: 272B rows, b128 frag reads spread over banks
#define TRB 32

__device__ __forceinline__ float lrelu(float x){ return x > 0.f ? x : 0.01f * x; }

__device__ __forceinline__ unsigned short f2bf(float x){
    union { float f; unsigned u; } c; c.f = x;
    unsigned u = c.u; u += 0x7fffu + ((u >> 16) & 1u);
    return (unsigned short)(u >> 16);
}

__device__ __forceinline__ bf16x8 ldA(const unsigned short* __restrict__ WT, int K,
                                      int m0, int kc, int lane){
    return *(const bf16x8*)(WT + (size_t)(m0 + (lane & 15)) * K + kc * 32 + (lane >> 4) * 8);
}
__device__ __forceinline__ bf16x8 ldB(const unsigned short* L, int n0, int kc, int lane){
    return *(const bf16x8*)(L + (n0 + (lane & 15)) * PITCH + kc * 32 + (lane >> 4) * 8);
}

template<int NMT, int NNT, int NKC>
__device__ __forceinline__ void mmT(const unsigned short* __restrict__ WT, int K, int M0,
                                    const unsigned short* Ls, int N0, int lane,
                                    f32x4 acc[NMT][NNT])
{
#pragma unroll
    for (int kc = 0; kc < NKC; ++kc) {
        bf16x8 b[NNT];
#pragma unroll
        for (int nt = 0; nt < NNT; ++nt) b[nt] = ldB(Ls, N0 + nt * 16, kc, lane);
#pragma unroll
        for (int mt = 0; mt < NMT; ++mt) {
            bf16x8 av = ldA(WT, K, M0 + mt * 16, kc, lane);
#pragma unroll
            for (int nt = 0; nt < NNT; ++nt)
                acc[mt][nt] = __builtin_amdgcn_mfma_f32_16x16x32_bf16(av, b[nt], acc[mt][nt], 0, 0, 0);
        }
    }
}

// prefetch helpers: sa slice for agent n (n = -1 => s_i columns; a-part then reads
// a[:,0:32] harmlessly and lands in unread LDS columns)
__device__ __forceinline__ void ld_sa(const float* __restrict__ s, const float* __restrict__ a,
                                      int row0, int n, int t, float4 sReg[3], float4& aReg){
#pragma unroll
    for (int i = 0; i < 3; ++i) {
        int idx = t + 256 * i; int r = idx / 24, c4 = idx % 24;
        sReg[i] = *(const float4*)(s + (size_t)(row0 + r) * 768 + 96 + 96 * n + c4 * 4);
    }
    aReg = *(const float4*)(a + (size_t)(row0 + (t >> 3)) * 256 + 32 + 32 * n + (t & 7) * 4);
}
__device__ __forceinline__ void st_sa(unsigned short* buf, int t,
                                      const float4 sReg[3], const float4 aReg){
#pragma unroll
    for (int i = 0; i < 3; ++i) {
        int idx = t + 256 * i; int r = idx / 24, c4 = idx % 24;
        ushort4 p; p.x = f2bf(sReg[i].x); p.y = f2bf(sReg[i].y);
        p.z = f2bf(sReg[i].z); p.w = f2bf(sReg[i].w);
        *(ushort4*)(buf + r * PITCH + c4 * 4) = p;
    }
    ushort4 p; p.x = f2bf(aReg.x); p.y = f2bf(aReg.y); p.z = f2bf(aReg.z); p.w = f2bf(aReg.w);
    *(ushort4*)(buf + (t >> 3) * PITCH + 96 + (t & 7) * 4) = p;
}

// ---- weight prep: fp32 W[in][out] -> bf16 W^T[out][in] packed in d_ws ----
__global__ void wprep(const float* __restrict__ Ws, const float* __restrict__ Wsa,
                      const float* __restrict__ Wq_, const float* __restrict__ Wk_,
                      const float* __restrict__ Wv_, const float* __restrict__ Wo_,
                      const float* __restrict__ W1, const float* __restrict__ W2,
                      unsigned short* __restrict__ o)
{
    int id = blockIdx.x * 256 + threadIdx.x;
    if (id >= 229376) return;
    float v;
    if (id < 12288)        { int q = id / 96, f = id - q * 96;                         v = Ws[f * 128 + q]; }
    else if (id < 126976)  { int li = id - 12288; int n = li >> 14; int r = li & 16383;
                             int q = r >> 7, f = r & 127;                              v = Wsa[n * 16384 + f * 128 + q]; }
    else if (id < 143360)  { int li = id - 126976; int q = li >> 7, f = li & 127;      v = Wq_[f * 128 + q]; }
    else if (id < 159744)  { int li = id - 143360; int q = li >> 7, f = li & 127;      v = Wk_[f * 128 + q]; }
    else if (id < 176128)  { int li = id - 159744; int q = li >> 7, f = li & 127;      v = Wv_[f * 128 + q]; }
    else if (id < 192512)  { int li = id - 176128; int q = li >> 7, f = li & 127;      v = Wo_[f * 128 + q]; }
    else if (id < 225280)  { int li = id - 192512; int q = li >> 8, f = li & 255;      v = W1[f * 128 + q]; }
    else                   { int li = id - 225280; int q = li >> 7, f = li & 127;      v = W2[f * 32 + q]; }
    o[id] = f2bf(v);
}

__global__ void __launch_bounds__(256, 4)
ac_mfma(const float* __restrict__ s, const float* __restrict__ a,
        const unsigned short* __restrict__ WS,
        const float* __restrict__ b_enc_s, const float* __restrict__ b_enc_sa,
        const float* __restrict__ bv, const float* __restrict__ bo,
        const float* __restrict__ b_fc1, const float* __restrict__ b_fc2,
        float* __restrict__ out_q, float* __restrict__ out_allq)
{
    // 4 x 8704B buffers = 34,816 B -> 4 blocks/CU by LDS
    __shared__ __align__(16) unsigned short SMEM[4 * TRB * PITCH];
    unsigned short* bufA = SMEM;                     // staging / attn / fc2-partial overlay
    unsigned short* sE0  = SMEM + TRB * PITCH;       // e (even n) / ov / fc2-partial overlay
    unsigned short* sE1  = SMEM + 2 * TRB * PITCH;   // e (odd n)  / allq stash overlay
    unsigned short* sENC = SMEM + 3 * TRB * PITCH;   // s_enc -> h1

    const int t = threadIdx.x, lane = t & 63, wid = t >> 6;
    const int l15 = lane & 15, l4 = lane >> 4;
    const int M0 = 32 * wid;
    const int row0 = blockIdx.x * TRB;
    const float rsd = 0.17677669529663687f;  // 1/sqrt(32)

    const unsigned short* WencST = WS;
    const unsigned short* WsaT   = WS + 12288;
    const unsigned short* WqT    = WS + 126976;
    const unsigned short* WkT    = WS + 143360;
    const unsigned short* WvT    = WS + 159744;
    const unsigned short* WoT    = WS + 176128;
    const unsigned short* W1T    = WS + 192512;
    const unsigned short* W2T    = WS + 225280;

    float4 sReg[3]; float4 aReg;

    // ---- prologue: stage s_i -> bufA ----
    ld_sa(s, a, row0, -1, t, sReg, aReg);
    st_sa(bufA, t, sReg, aReg);
    __syncthreads();

    // ---- s_enc = lrelu(s_i @ Wenc_s + b) ----
    f32x4 acc[2][2];
#pragma unroll
    for (int mt = 0; mt < 2; ++mt)
#pragma unroll
        for (int nt = 0; nt < 2; ++nt) acc[mt][nt] = (f32x4){0.f, 0.f, 0.f, 0.f};
    mmT<2, 2, 3>(WencST, 96, M0, bufA, 0, lane, acc);
    ld_sa(s, a, row0, 0, t, sReg, aReg);     // prefetch agent 0
    __syncthreads();                          // all encS reads of bufA done
#pragma unroll
    for (int mt = 0; mt < 2; ++mt) {
        float4 bb = *(const float4*)(b_enc_s + M0 + mt * 16 + l4 * 4);
#pragma unroll
        for (int nt = 0; nt < 2; ++nt) {
            ushort4 p;
            p.x = f2bf(lrelu(acc[mt][nt][0] + bb.x));
            p.y = f2bf(lrelu(acc[mt][nt][1] + bb.y));
            p.z = f2bf(lrelu(acc[mt][nt][2] + bb.z));
            p.w = f2bf(lrelu(acc[mt][nt][3] + bb.w));
            *(ushort4*)(sENC + (nt * 16 + l15) * PITCH + M0 + mt * 16 + l4 * 4) = p;
        }
    }
    st_sa(bufA, t, sReg, aReg);
    __syncthreads();                          // sENC + stage(agent0) visible

    // ---- Q (stays in registers; wave wid == head wid) ----
    f32x4 q[2][2];
#pragma unroll
    for (int mt = 0; mt < 2; ++mt)
#pragma unroll
        for (int nt = 0; nt < 2; ++nt) q[mt][nt] = (f32x4){0.f, 0.f, 0.f, 0.f};
    mmT<2, 2, 4>(WqT, 128, M0, sENC, 0, lane, q);

    float4 bvf[2];
#pragma unroll
    for (int mt = 0; mt < 2; ++mt) bvf[mt] = *(const float4*)(bv + M0 + mt * 16 + l4 * 4);

    f32x4 atn[2][2];
#pragma unroll
    for (int mt = 0; mt < 2; ++mt)
#pragma unroll
        for (int nt = 0; nt < 2; ++nt) atn[mt][nt] = (f32x4){0.f, 0.f, 0.f, 0.f};
    float m_[2] = {-INFINITY, -INFINITY}, l_[2] = {0.f, 0.f};

    // ---- online attention, 2 barriers / agent ----
    for (int n = 0; n < 7; ++n) {
        unsigned short* eb = (n & 1) ? sE1 : sE0;
        if (n < 6) ld_sa(s, a, row0, n + 1, t, sReg, aReg);   // issue early

        f32x4 e[2][2];
#pragma unroll
        for (int mt = 0; mt < 2; ++mt)
#pragma unroll
            for (int nt = 0; nt < 2; ++nt) e[mt][nt] = (f32x4){0.f, 0.f, 0.f, 0.f};
        mmT<2, 2, 4>(WsaT + n * 16384, 128, M0, bufA, 0, lane, e);
        __syncthreads();                      // A(n): all e-mm reads of bufA done

#pragma unroll
        for (int mt = 0; mt < 2; ++mt) {
            float4 bb = *(const float4*)(b_enc_sa + n * 128 + M0 + mt * 16 + l4 * 4);
#pragma unroll
            for (int nt = 0; nt < 2; ++nt) {
                ushort4 p;
                p.x = f2bf(lrelu(e[mt][nt][0] + bb.x));
                p.y = f2bf(lrelu(e[mt][nt][1] + bb.y));
                p.z = f2bf(lrelu(e[mt][nt][2] + bb.z));
                p.w = f2bf(lrelu(e[mt][nt][3] + bb.w));
                *(ushort4*)(eb + (nt * 16 + l15) * PITCH + M0 + mt * 16 + l4 * 4) = p;
            }
        }
        if (n < 6) st_sa(bufA, t, sReg, aReg);  // write-late
        __syncthreads();                      // B(n): e + next stage visible

        // K, scores, softmax
        f32x4 kv[2][2];
#pragma unroll
        for (int mt = 0; mt < 2; ++mt)
#pragma unroll
            for (int nt = 0; nt < 2; ++nt) kv[mt][nt] = (f32x4){0.f, 0.f, 0.f, 0.f};
        mmT<2, 2, 4>(WkT, 128, M0, eb, 0, lane, kv);

        float pr[2], corr[2];
#pragma unroll
        for (int nt = 0; nt < 2; ++nt) {
            float p = 0.f;
#pragma unroll
            for (int mt = 0; mt < 2; ++mt)
#pragma unroll
                for (int r = 0; r < 4; ++r) p = fmaf(q[mt][nt][r], kv[mt][nt][r], p);
            p += __shfl_xor(p, 16);
            p += __shfl_xor(p, 32);
            float sc = p * rsd;
            float mo = m_[nt], mn = fmaxf(mo, sc);
            pr[nt]   = __expf(sc - mn);
            corr[nt] = __expf(mo - mn);
            l_[nt] = l_[nt] * corr[nt] + pr[nt];
            m_[nt] = mn;
        }

        // V, online accumulate
#pragma unroll
        for (int mt = 0; mt < 2; ++mt)
#pragma unroll
            for (int nt = 0; nt < 2; ++nt) kv[mt][nt] = (f32x4){0.f, 0.f, 0.f, 0.f};
        mmT<2, 2, 4>(WvT, 128, M0, eb, 0, lane, kv);
#pragma unroll
        for (int mt = 0; mt < 2; ++mt)
#pragma unroll
            for (int nt = 0; nt < 2; ++nt)
#pragma unroll
                for (int r = 0; r < 4; ++r) {
                    float vv = lrelu(kv[mt][nt][r] + ((const float*)&bvf[mt])[r]);
                    atn[mt][nt][r] = fmaf(atn[mt][nt][r], corr[nt], pr[nt] * vv);
                }
    }

    // ---- attn/l -> bufA (stage dead) ----
#pragma unroll
    for (int mt = 0; mt < 2; ++mt)
#pragma unroll
        for (int nt = 0; nt < 2; ++nt) {
            float inv = 1.f / l_[nt];
            ushort4 p;
            p.x = f2bf(atn[mt][nt][0] * inv);
            p.y = f2bf(atn[mt][nt][1] * inv);
            p.z = f2bf(atn[mt][nt][2] * inv);
            p.w = f2bf(atn[mt][nt][3] * inv);
            *(ushort4*)(bufA + (nt * 16 + l15) * PITCH + M0 + mt * 16 + l4 * 4) = p;
        }
    __syncthreads();

    // ---- ov = attn @ Wo + bo -> sE0 ----
#pragma unroll
    for (int mt = 0; mt < 2; ++mt)
#pragma unroll
        for (int nt = 0; nt < 2; ++nt) acc[mt][nt] = (f32x4){0.f, 0.f, 0.f, 0.f};
    mmT<2, 2, 4>(WoT, 128, M0, bufA, 0, lane, acc);
#pragma unroll
    for (int mt = 0; mt < 2; ++mt) {
        float4 bb = *(const float4*)(bo + M0 + mt * 16 + l4 * 4);
#pragma unroll
        for (int nt = 0; nt < 2; ++nt) {
            ushort4 p;
            p.x = f2bf(acc[mt][nt][0] + bb.x);
            p.y = f2bf(acc[mt][nt][1] + bb.y);
            p.z = f2bf(acc[mt][nt][2] + bb.z);
            p.w = f2bf(acc[mt][nt][3] + bb.w);
            *(ushort4*)(sE0 + (nt * 16 + l15) * PITCH + M0 + mt * 16 + l4 * 4) = p;
        }
    }
    __syncthreads();

    // ---- h1 = lrelu([s_enc | ov] @ W_fc1 + b1) ----
#pragma unroll
    for (int mt = 0; mt < 2; ++mt)
#pragma unroll
        for (int nt = 0; nt < 2; ++nt) acc[mt][nt] = (f32x4){0.f, 0.f, 0.f, 0.f};
    mmT<2, 2, 4>(W1T, 256, M0, sENC, 0, lane, acc);
    mmT<2, 2, 4>(W1T + 128, 256, M0, sE0, 0, lane, acc);
    __syncthreads();                          // fc1 reads of sENC/sE0 done
#pragma unroll
    for (int mt = 0; mt < 2; ++mt) {
        float4 bb = *(const float4*)(b_fc1 + M0 + mt * 16 + l4 * 4);
#pragma unroll
        for (int nt = 0; nt < 2; ++nt) {
            ushort4 p;
            p.x = f2bf(lrelu(acc[mt][nt][0] + bb.x));
            p.y = f2bf(lrelu(acc[mt][nt][1] + bb.y));
            p.z = f2bf(lrelu(acc[mt][nt][2] + bb.z));
            p.w = f2bf(lrelu(acc[mt][nt][3] + bb.w));
            *(ushort4*)(sENC + (nt * 16 + l15) * PITCH + M0 + mt * 16 + l4 * 4) = p;
        }
    }
    __syncthreads();                          // h1 visible

    // ---- all_q = h1 @ W_fc2 + b2 : wave wid takes K-chunk kc=wid, partials in LDS ----
    float* P = (float*)SMEM;                  // 4096 f32 overlay on bufA+sE0 (dead)
    {
        bf16x8 a0 = ldA(W2T, 128, 0, wid, lane);
        bf16x8 a1 = ldA(W2T, 128, 16, wid, lane);
        bf16x8 b0 = ldB(sENC, 0, wid, lane);
        bf16x8 b1 = ldB(sENC, 16, wid, lane);
        f32x4 z = (f32x4){0.f, 0.f, 0.f, 0.f};
        f32x4 c00 = __builtin_amdgcn_mfma_f32_16x16x32_bf16(a0, b0, z, 0, 0, 0);
        f32x4 c01 = __builtin_amdgcn_mfma_f32_16x16x32_bf16(a0, b1, z, 0, 0, 0);
        f32x4 c10 = __builtin_amdgcn_mfma_f32_16x16x32_bf16(a1, b0, z, 0, 0, 0);
        f32x4 c11 = __builtin_amdgcn_mfma_f32_16x16x32_bf16(a1, b1, z, 0, 0, 0);
        // P[wid][row][f]
        *(f32x4*)(P + wid * 1024 + (l15     ) * 32 +      l4 * 4) = c00;
        *(f32x4*)(P + wid * 1024 + (16 + l15) * 32 +      l4 * 4) = c01;
        *(f32x4*)(P + wid * 1024 + (l15     ) * 32 + 16 + l4 * 4) = c10;
        *(f32x4*)(P + wid * 1024 + (16 + l15) * 32 + 16 + l4 * 4) = c11;
    }
    __syncthreads();

    float* S = (float*)SMEM + 4352;           // stash [32][33] overlay on sE1 (dead)
#pragma unroll
    for (int j = 0; j < 4; ++j) {
        int o = t + 256 * j; int row = o >> 5, f = o & 31;
        float v = P[row * 32 + f] + P[1024 + row * 32 + f]
                + P[2048 + row * 32 + f] + P[3072 + row * 32 + f] + b_fc2[f];
        out_allq[(size_t)(row0 + row) * 32 + f] = v;
        S[row * 33 + f] = v;
    }
    __syncthreads();

    // ---- q = all_q[argmax(a[:, :32])] ----
    if (t < TRB) {
        int row = row0 + t;
        const float4* ar = (const float4*)(a + (size_t)row * 256);
        float best = -INFINITY; int bi = 0;
#pragma unroll
        for (int jj = 0; jj < 8; ++jj) {
            float4 v = ar[jj];
            float vv[4] = {v.x, v.y, v.z, v.w};
#pragma unroll
            for (int e2 = 0; e2 < 4; ++e2)
                if (vv[e2] > best) { best = vv[e2]; bi = jj * 4 + e2; }
        }
        out_q[row] = S[t * 33 + bi];
    }
}

extern "C" void kernel_launch(void* const* d_in, const int* in_sizes, int n_in,
                              void* d_out, int out_size, void* d_ws, size_t ws_size,
                              hipStream_t stream)
{
    (void)n_in; (void)out_size; (void)ws_size;
    const float* s        = (const float*)d_in[0];
    const float* a        = (const float*)d_in[1];
    const float* W_enc_s  = (const float*)d_in[2];
    const float* b_enc_s  = (const float*)d_in[3];
    const float* W_enc_sa = (const float*)d_in[4];
    const float* b_enc_sa = (const float*)d_in[5];
    const float* Wq       = (const float*)d_in[6];
    const float* Wk       = (const float*)d_in[7];
    const float* Wv       = (const float*)d_in[8];
    const float* bv       = (const float*)d_in[9];
    const float* Wo       = (const float*)d_in[10];
    const float* bo       = (const float*)d_in[11];
    const float* W_fc1    = (const float*)d_in[12];
    const float* b_fc1    = (const float*)d_in[13];
    const float* W_fc2    = (const float*)d_in[14];
    const float* b_fc2    = (const float*)d_in[15];

    int B = in_sizes[0] / 768;
    float* out_q    = (float*)d_out;
    float* out_allq = out_q + B;
    unsigned short* WS = (unsigned short*)d_ws;

    wprep<<<dim3(896), dim3(256), 0, stream>>>(W_enc_s, W_enc_sa, Wq, Wk, Wv, Wo,
                                               W_fc1, W_fc2, WS);
    ac_mfma<<<dim3(B / TRB), dim3(256), 0, stream>>>(s, a, WS, b_enc_s, b_enc_sa,
                                                     bv, bo, b_fc1, b_fc2,
                                                     out_q, out_allq);
}